// Round 17
// baseline (493.827 us; speedup 1.0000x reference)
//
#include <hip/hip_runtime.h>
#include <stdint.h>

#define NN 50000
#define CC 1024
#define HH 128
#define EE 1600000
#define EPSV 1e-8f
#define SCAN_BLKS 196        // ceil(NN/256)
#define ENC_BLKS 782         // encoder tile blocks (64 rows)
#define UV_BLKS 782
#define EDGE_BLKS (EE/256)   // 6250
#define CONV_BLKS 25000      // X->bf16: 51.2M elems / (256*8)
#define PREP_BLKS 704        // weight prep span

typedef __attribute__((ext_vector_type(8))) short bf16x8;
typedef __attribute__((ext_vector_type(4))) float f32x4;
typedef __attribute__((ext_vector_type(2))) float f32x2;

__device__ __forceinline__ unsigned short f32_to_bf16(float f){
  union { float f; uint32_t u; } cv; cv.f = f;
  uint32_t u = cv.u;
  return (unsigned short)((u + 0x7FFFu + ((u >> 16) & 1u)) >> 16);
}
__device__ __forceinline__ float bf16lo_to_f32(uint32_t w){
  union { uint32_t u; float f; } cv; cv.u = w << 16; return cv.f;
}
__device__ __forceinline__ float bf16hi_to_f32(uint32_t w){
  union { uint32_t u; float f; } cv; cv.u = w & 0xFFFF0000u; return cv.f;
}

// DPP cross-lane add within a 16-lane row (xor1, xor2, ^7-in-8, mirror-16)
#define DPP_ADD(x, ctrl) ((x) + __int_as_float(__builtin_amdgcn_update_dpp(0, __float_as_int(x), (ctrl), 0xF, 0xF, true)))

// async global->LDS 16B DMA
#define GLOAD_LDS16(g, l) __builtin_amdgcn_global_load_lds( \
    (const __attribute__((address_space(1))) uint32_t*)(g), \
    (__attribute__((address_space(3))) uint32_t*)(l), 16, 0, 0)

// ---------------- FUSED: hist (FIRST: latency-bound fills CUs early) + prep + X->bf16 ----------------

__global__ __launch_bounds__(256) void k_conv_hist_prep(
    const float* __restrict__ X, unsigned short* __restrict__ Xb,
    const int* __restrict__ src, const int* __restrict__ dst,
    int* __restrict__ counts, int* __restrict__ rank,
    const float* __restrict__ W1, const float* __restrict__ W2,
    const float* __restrict__ Wg1,
    unsigned short* __restrict__ W1T, unsigned short* __restrict__ W2T,
    unsigned short* __restrict__ Wg1T)
{
  const int b = blockIdx.x;
  if(b < EDGE_BLKS){                       // hist + rank (dispatched first)
    int e = b*256 + threadIdx.x;
    if(e < EE) rank[e] = atomicAdd(&counts[dst[e]], 1);
    return;
  }
  if(b < EDGE_BLKS + PREP_BLKS){           // weight prep
    int idx = (b - EDGE_BLKS)*256 + threadIdx.x;
    if(idx < 131072){                                 // W1T[n][k] = W1[k][n]
      int n = idx >> 10, k = idx & 1023;
      W1T[idx] = f32_to_bf16(W1[k*128 + n]);
    } else if(idx < 131072 + 16384){                  // W2T[n][k] = W2[k][n]
      int i = idx - 131072;
      int n = i >> 7, k = i & 127;
      W2T[i] = f32_to_bf16(W2[k*128 + n]);
    } else if(idx < 131072 + 16384 + 32768){          // Wg1T[c][k]
      int i = idx - 131072 - 16384;
      int c = i >> 7, k = i & 127;
      int row = (c < 128) ? k : (128 + k);
      int col = (c < 128) ? c : (c - 128);
      Wg1T[i] = f32_to_bf16(Wg1[row*128 + col]);
    }
    return;
  }
  // streaming X -> bf16 (runs under/behind the hist blocks)
  const size_t i = (((size_t)(b - EDGE_BLKS - PREP_BLKS))*256 + threadIdx.x)*8;
  f32x4 v0 = *(const f32x4*)(X + i);
  f32x4 v1 = *(const f32x4*)(X + i + 4);
  union { bf16x8 v; unsigned short s[8]; } pk;
  #pragma unroll
  for(int j = 0; j < 4; j++){ pk.s[j] = f32_to_bf16(v0[j]); pk.s[4+j] = f32_to_bf16(v1[j]); }
  *(bf16x8*)(Xb + i) = pk.v;
}

// ---------------- scans over NN dst counts (2 launches) ----------------

__global__ __launch_bounds__(256) void k_scan1(const int* __restrict__ counts,
    int* __restrict__ lexcl, int* __restrict__ bsum){
  __shared__ int buf[256];
  const int t = threadIdx.x, i = blockIdx.x*256 + t;
  int v = (i < NN) ? counts[i] : 0;
  buf[t] = v;
  __syncthreads();
  for(int off = 1; off < 256; off <<= 1){
    int add = (t >= off) ? buf[t-off] : 0;
    __syncthreads();
    buf[t] += add;
    __syncthreads();
  }
  if(i < NN) lexcl[i] = buf[t] - v;
  if(t == 255) bsum[blockIdx.x] = buf[255];
}

// merged: each block reduces its bsum prefix locally, then adds to lexcl
__global__ __launch_bounds__(256) void k_scan3(const int* __restrict__ lexcl,
    const int* __restrict__ bsum, int* __restrict__ row_ptr){
  __shared__ int red[256];
  const int t = threadIdx.x, b = blockIdx.x;
  red[t] = (t < b) ? bsum[t] : 0;     // b < 196 <= 256
  __syncthreads();
  for(int off = 1; off < 256; off <<= 1){
    int add = (t >= off) ? red[t-off] : 0;
    __syncthreads();
    red[t] += add;
    __syncthreads();
  }
  const int bexcl = red[255];
  const int i = b*256 + t;
  if(i < NN) row_ptr[i] = lexcl[i] + bexcl;
  if(i == 0) row_ptr[NN] = EE;
}

// ---------------- FUSED: encoder GEMM1 (bf16 A) + CSR fill ----------------
// enc1: 64-row tile, A bf16 from Xb, B bf16 W1T. 2-buffer global_load_lds
// pipeline, counted vmcnt(3). Swizzle key (row^(row>>2))&3 on 16B chunks.
// fill (blocks >= ENC_BLKS): p = row_ptr[dst]+rank; scp[p] = {c, src}.

__global__ __launch_bounds__(256) void k_enc1_fill(
    const unsigned short* __restrict__ Xb, const unsigned short* __restrict__ W1T,
    const float* __restrict__ b1, unsigned short* __restrict__ h1,
    const int* __restrict__ src, const int* __restrict__ dst,
    const float* __restrict__ base_w, const float* __restrict__ rho_raw,
    const int* __restrict__ row_ptr, const int* __restrict__ rank,
    float2* __restrict__ scp)
{
  __shared__ __attribute__((aligned(16))) unsigned short Ab[2][64*32];    // 4KB each
  __shared__ __attribute__((aligned(16))) unsigned short Bf[2][128*32];   // 8KB each

  if(blockIdx.x >= ENC_BLKS){
    int e = (blockIdx.x - ENC_BLKS)*256 + threadIdx.x;
    if(e < EE){
      int s = src[e], d = dst[e];
      int p = row_ptr[d] + rank[e];
      float rs = 1.f/(1.f + __expf(-rho_raw[s]));
      float rd = 1.f/(1.f + __expf(-rho_raw[d]));
      scp[p] = make_float2(base_w[e]*rs*rd, __int_as_float(s));
    }
    return;
  }

  const int t = threadIdx.x, w = t >> 6, lane = t & 63;
  const int rowL = lane & 15, kq = lane >> 4;
  const int wm = w >> 1, wn = w & 1;
  const int row0 = blockIdx.x * 64;

  const int a_rl  = w*16 + (lane >> 2);
  const int a_cl  = lane & 3;
  const int akeyW = (a_rl ^ (a_rl >> 2)) & 3;
  int agr = row0 + a_rl; if(agr >= NN) agr = NN-1;
  const unsigned short* a_src = Xb + (size_t)agr*1024 + (a_cl ^ akeyW)*8;
  const int b_rl0 = w*32 + (lane >> 2);
  const int b_cl  = lane & 3;
  const int bkey0 = (b_rl0 ^ (b_rl0 >> 2)) & 3;
  const int bkey1 = ((b_rl0+16) ^ ((b_rl0+16) >> 2)) & 3;
  const unsigned short* b_src0 = W1T + (size_t)b_rl0*1024 + (b_cl ^ bkey0)*8;
  const unsigned short* b_src1 = W1T + (size_t)(b_rl0+16)*1024 + (b_cl ^ bkey1)*8;

  #define STAGE(buf, k0)  do{                                              \
    GLOAD_LDS16(a_src  + (k0), &Ab[buf][(w*16)*32]);                       \
    GLOAD_LDS16(b_src0 + (k0), &Bf[buf][(w*32     )*32]);                  \
    GLOAD_LDS16(b_src1 + (k0), &Bf[buf][(w*32 + 16)*32]);                  \
  }while(0)

  f32x4 acc[2][4] = {};
  const int arow0 = wm*32 + rowL;
  const int keyR  = (rowL ^ (rowL >> 2)) & 3;

  auto COMPUTE = [&](const unsigned short* afb, const unsigned short* bfb){
    bf16x8 af[2];
    #pragma unroll
    for(int mf = 0; mf < 2; mf++)
      af[mf] = *(const bf16x8*)&afb[(arow0 + mf*16)*32 + ((kq ^ keyR) << 3)];
    bf16x8 bfr[4];
    #pragma unroll
    for(int nf = 0; nf < 4; nf++){
      const int br = wn*64 + nf*16 + rowL;
      bfr[nf] = *(const bf16x8*)&bfb[br*32 + ((kq ^ keyR) << 3)];
    }
    #pragma unroll
    for(int mf = 0; mf < 2; mf++)
      #pragma unroll
      for(int nf = 0; nf < 4; nf++)
        acc[mf][nf] = __builtin_amdgcn_mfma_f32_16x16x32_bf16(af[mf], bfr[nf], acc[mf][nf], 0, 0, 0);
  };

  #define STEP(cbuf, sbuf, sk)  do{                                        \
    STAGE(sbuf, (sk)*32);                                                  \
    asm volatile("s_waitcnt vmcnt(3)" ::: "memory");                       \
    __builtin_amdgcn_s_barrier();                                          \
    __builtin_amdgcn_sched_barrier(0);                                     \
    COMPUTE(&Ab[cbuf][0], &Bf[cbuf][0]);                                   \
    __builtin_amdgcn_s_barrier();                                          \
  }while(0)

  STAGE(0, 0);
  for(int tt = 0; tt < 30; tt += 2){
    STEP(0, 1, tt + 1);
    STEP(1, 0, tt + 2);
  }
  STEP(0, 1, 31);
  asm volatile("s_waitcnt vmcnt(0)" ::: "memory");
  __builtin_amdgcn_s_barrier();
  __builtin_amdgcn_sched_barrier(0);
  COMPUTE(&Ab[1][0], &Bf[1][0]);
  #undef STEP
  #undef STAGE

  #pragma unroll
  for(int mf = 0; mf < 2; mf++){
    #pragma unroll
    for(int nf = 0; nf < 4; nf++){
      const int col = wn*64 + nf*16 + rowL;
      const float bv = b1[col];
      #pragma unroll
      for(int r = 0; r < 4; r++){
        const int gr = row0 + wm*32 + mf*16 + kq*4 + r;
        if(gr < NN) h1[(size_t)gr*128 + col] = f32_to_bf16(fmaxf(acc[mf][nf][r] + bv, 0.f));
      }
    }
  }
}

// ---------------- UV phase 2, B-in-registers: wave w owns output cols [64w,64w+64) ----------------
// hs: 64 rows x 128 bf16 swizzled (chunk c of row r at c^(r&15)). B-frags from
// L2-resident Wg1T held in 64 VGPR; 4 M-subtiles iterated from LDS. No wgl LDS.

__device__ __forceinline__ void uv_phase2(
    const unsigned short* hs, int row0, int w, int lane,
    const unsigned short* __restrict__ Wg1T, const float* __restrict__ bg1,
    unsigned short* __restrict__ UH, float* __restrict__ Vf)
{
  const int rowL = lane & 15, kq = lane >> 4;
  bf16x8 breg[4][4];
  #pragma unroll
  for(int nt = 0; nt < 4; nt++)
    #pragma unroll
    for(int ks = 0; ks < 4; ks++)
      breg[nt][ks] = *(const bf16x8*)(Wg1T + (size_t)(w*64 + nt*16 + rowL)*128 + ks*32 + kq*8);

  #pragma unroll
  for(int mt = 0; mt < 4; mt++){
    const int r = mt*16 + rowL;
    f32x4 acc[4] = {};
    #pragma unroll
    for(int ks = 0; ks < 4; ks++){
      const int kc = ks*4 + kq;
      bf16x8 a = *(const bf16x8*)&hs[r*128 + ((kc ^ rowL) << 3)];
      #pragma unroll
      for(int nt = 0; nt < 4; nt++)
        acc[nt] = __builtin_amdgcn_mfma_f32_16x16x32_bf16(a, breg[nt][ks], acc[nt], 0, 0, 0);
    }
    #pragma unroll
    for(int nt = 0; nt < 4; nt++){
      const int col = w*64 + nt*16 + rowL;
      #pragma unroll
      for(int rr = 0; rr < 4; rr++){
        const int gr = row0 + mt*16 + kq*4 + rr;
        if(gr < NN){
          if(col < 128) UH[(size_t)gr*256 + col] = f32_to_bf16(acc[nt][rr]);
          else          Vf[(size_t)gr*128 + col - 128] = acc[nt][rr] + bg1[col - 128];
        }
      }
    }
  }
}

// ---------------- k_uvA: h = relu(h1@W2T + b2); writes UH_A=[u|h], Vf ----------------

__global__ __launch_bounds__(256) void k_uvA(
    const unsigned short* __restrict__ h1, const unsigned short* __restrict__ W2T,
    const float* __restrict__ b2, const unsigned short* __restrict__ Wg1T,
    const float* __restrict__ bg1, unsigned short* __restrict__ UH,
    float* __restrict__ Vf)
{
  __shared__ __attribute__((aligned(16))) unsigned short hs[64*128];   // 16 KB
  const int t = threadIdx.x, wave = t >> 6, lane = t & 63;
  const int rowL = lane & 15, kq = lane >> 4;
  const int row0 = blockIdx.x*64;

  // phase 1: h = relu(h1 @ W2T + b2); wave's 16-row slice
  int ar = row0 + wave*16 + rowL; if(ar >= NN) ar = NN-1;
  f32x4 acc[8] = {};
  #pragma unroll
  for(int ks = 0; ks < 4; ks++){
    bf16x8 a = *(const bf16x8*)(h1 + (size_t)ar*128 + ks*32 + kq*8);
    #pragma unroll
    for(int nt = 0; nt < 8; nt++){
      bf16x8 b = *(const bf16x8*)(W2T + (nt*16 + rowL)*128 + ks*32 + kq*8);
      acc[nt] = __builtin_amdgcn_mfma_f32_16x16x32_bf16(a, b, acc[nt], 0, 0, 0);
    }
  }
  #pragma unroll
  for(int nt = 0; nt < 8; nt++){
    const int col = nt*16 + rowL;
    const float bv = b2[col];
    #pragma unroll
    for(int r = 0; r < 4; r++){
      const int rw = wave*16 + kq*4 + r;
      const unsigned short hv = f32_to_bf16(fmaxf(acc[nt][r] + bv, 0.f));
      hs[rw*128 + (((col >> 3) ^ (rw & 15)) << 3) + (col & 7)] = hv;
    }
  }
  __syncthreads();
  // copy h to UH h-half (coalesced 16B)
  {
    const int r = t >> 2, gr = row0 + r;
    if(gr < NN){
      #pragma unroll
      for(int j8 = 0; j8 < 4; j8++){
        const int chunk = (t & 3)*4 + j8;
        bf16x8 v = *(const bf16x8*)&hs[r*128 + ((chunk ^ (r & 15)) << 3)];
        *(bf16x8*)&UH[(size_t)gr*256 + 128 + chunk*8] = v;
      }
    }
  }
  uv_phase2(hs, row0, wave, lane, Wg1T, bg1, UH, Vf);
}

// ---------------- k_uvB: reads UH_B h-half (bf16); computes u,v in place ----------------

__global__ __launch_bounds__(256) void k_uvB(
    const unsigned short* __restrict__ Wg1T, const float* __restrict__ bg1,
    unsigned short* __restrict__ UH, float* __restrict__ Vf)
{
  __shared__ __attribute__((aligned(16))) unsigned short hs[64*128];   // 16 KB
  const int t = threadIdx.x, wave = t >> 6, lane = t & 63;
  const int row0 = blockIdx.x*64;

  {
    const int r = t >> 2, gr0 = row0 + r;
    const int gr = (gr0 < NN) ? gr0 : NN-1;
    const unsigned short* p = UH + (size_t)gr*256 + 128 + (t & 3)*32;
    #pragma unroll
    for(int j8 = 0; j8 < 4; j8++){
      bf16x8 v = *(const bf16x8*)(p + j8*8);
      const int chunk = (t & 3)*4 + j8;
      *(bf16x8*)&hs[r*128 + ((chunk ^ (r & 15)) << 3)] = v;
    }
  }
  __syncthreads();
  uv_phase2(hs, row0, wave, lane, Wg1T, bg1, UH, Vf);
}

// ---------------- fused gate + aggregation, CSR, one wave per dst ----------------

__global__ __launch_bounds__(256) void k_gate_agg(
    const unsigned short* __restrict__ UH, const float* __restrict__ Vf,
    const int* __restrict__ row_ptr, const float2* __restrict__ scp,
    const float* __restrict__ Wg2, const float* __restrict__ bg2p,
    float* __restrict__ out_f32, unsigned short* __restrict__ uh_out)
{
  __shared__ float2 ws_s[4][64];
  const int wv = threadIdx.x >> 6, lane = threadIdx.x & 63;
  const int gw = blockIdx.x*4 + wv;
  if(gw >= NN) return;
  const int eq = lane >> 4, li = lane & 15;

  f32x4 va = *(const f32x4*)(Vf + (size_t)gw*128 + li*8);
  f32x4 vb = *(const f32x4*)(Vf + (size_t)gw*128 + li*8 + 4);
  f32x4 wa = *(const f32x4*)(Wg2 + li*8);
  f32x4 wb = *(const f32x4*)(Wg2 + li*8 + 4);
  const float vch[8]  = {va[0],va[1],va[2],va[3],vb[0],vb[1],vb[2],vb[3]};
  const float w2ch[8] = {wa[0],wa[1],wa[2],wa[3],wb[0],wb[1],wb[2],wb[3]};
  const float bg2v = bg2p[0];

  const int beg = row_ptr[gw], end = row_ptr[gw+1];
  float a0 = 0.f, a1 = 0.f, wsum = 0.f;

  for(int base = beg; base < end; base += 64){
    const int nb = min(64, end - base);

    float2 sc_c0, sc_c1; bf16x8 u_c0, u_c1;
    {
      const int i0 = (eq     < nb) ? eq     : 0;
      const int i1 = (4 + eq < nb) ? 4 + eq : 0;
      sc_c0 = scp[base + i0]; sc_c1 = scp[base + i1];
      u_c0 = *(const bf16x8*)&UH[(uint32_t)__float_as_int(sc_c0.y)*256u + li*8];
      u_c1 = *(const bf16x8*)&UH[(uint32_t)__float_as_int(sc_c1.y)*256u + li*8];
    }
    for(int q = 0; q < nb; q += 8){
      float2 sc_n0 = sc_c0, sc_n1 = sc_c1; bf16x8 u_n0 = u_c0, u_n1 = u_c1;
      if(q + 8 < nb){
        const int i0 = (q + 8  + eq < nb) ? q + 8  + eq : 0;
        const int i1 = (q + 12 + eq < nb) ? q + 12 + eq : 0;
        sc_n0 = scp[base + i0]; sc_n1 = scp[base + i1];
        u_n0 = *(const bf16x8*)&UH[(uint32_t)__float_as_int(sc_n0.y)*256u + li*8];
        u_n1 = *(const bf16x8*)&UH[(uint32_t)__float_as_int(sc_n1.y)*256u + li*8];
      }
      { // edge A: idx = q + eq
        union { bf16x8 v; uint32_t u32[4]; } uu; uu.v = u_c0;
        float tacc = 0.f;
        #pragma unroll
        for(int p = 0; p < 4; p++){
          const uint32_t w2b = uu.u32[p];
          tacc += fmaxf(bf16lo_to_f32(w2b) + vch[2*p],   0.f) * w2ch[2*p];
          tacc += fmaxf(bf16hi_to_f32(w2b) + vch[2*p+1], 0.f) * w2ch[2*p+1];
        }
        tacc = DPP_ADD(tacc, 0xB1);
        tacc = DPP_ADD(tacc, 0x4E);
        tacc = DPP_ADD(tacc, 0x141);
        tacc = DPP_ADD(tacc, 0x140);
        const float g = 1.f/(1.f + __expf(-(tacc + bg2v)));
        const int idx = q + eq;
        if(li == 0 && idx < nb) ws_s[wv][idx] = make_float2(sc_c0.x*g, sc_c0.y);
      }
      { // edge B: idx = q + 4 + eq
        union { bf16x8 v; uint32_t u32[4]; } uu; uu.v = u_c1;
        float tacc = 0.f;
        #pragma unroll
        for(int p = 0; p < 4; p++){
          const uint32_t w2b = uu.u32[p];
          tacc += fmaxf(bf16lo_to_f32(w2b) + vch[2*p],   0.f) * w2ch[2*p];
          tacc += fmaxf(bf16hi_to_f32(w2b) + vch[2*p+1], 0.f) * w2ch[2*p+1];
        }
        tacc = DPP_ADD(tacc, 0xB1);
        tacc = DPP_ADD(tacc, 0x4E);
        tacc = DPP_ADD(tacc, 0x141);
        tacc = DPP_ADD(tacc, 0x140);
        const float g = 1.f/(1.f + __expf(-(tacc + bg2v)));
        const int idx = q + 4 + eq;
        if(li == 0 && idx < nb) ws_s[wv][idx] = make_float2(sc_c1.x*g, sc_c1.y);
      }
      sc_c0 = sc_n0; sc_c1 = sc_n1; u_c0 = u_n0; u_c1 = u_n1;
    }

    #pragma unroll 8
    for(int j = 0; j < nb; j++){
      const float2 p = ws_s[wv][j];
      const float w  = p.x;
      const uint32_t s = (uint32_t)__float_as_int(p.y);
      const uint32_t hw = *(const uint32_t*)&UH[s*256u + 128u + lane*2];
      a0 += w*bf16lo_to_f32(hw);
      a1 += w*bf16hi_to_f32(hw);
      wsum += w;
    }
  }
  const float inv = 1.f/(wsum + EPSV);
  const float r0 = a0*inv, r1 = a1*inv;
  if(uh_out){
    const uint32_t packed = (uint32_t)f32_to_bf16(r0) | ((uint32_t)f32_to_bf16(r1) << 16);
    *(uint32_t*)&uh_out[(size_t)gw*256 + 128 + lane*2] = packed;
  } else {
    const size_t o = (size_t)gw*128 + lane*2;
    *(f32x2*)&out_f32[o] = (f32x2){r0, r1};
  }
}

// ---------------- launch ----------------

extern "C" void kernel_launch(void* const* d_in, const int* in_sizes, int n_in,
                              void* d_out, int out_size, void* d_ws, size_t ws_size,
                              hipStream_t stream) {
  (void)in_sizes; (void)n_in; (void)out_size; (void)ws_size;
  const float* X      = (const float*)d_in[0];
  const int*   src    = (const int*)d_in[1];
  const int*   dst    = (const int*)d_in[2];
  const float* base_w = (const float*)d_in[3];
  const float* W1     = (const float*)d_in[4];
  const float* b1     = (const float*)d_in[5];
  const float* W2     = (const float*)d_in[6];
  const float* b2     = (const float*)d_in[7];
  const float* Wg1    = (const float*)d_in[8];
  const float* bg1    = (const float*)d_in[9];
  const float* Wg2    = (const float*)d_in[10];
  const float* bg2    = (const float*)d_in[11];
  const float* rho    = (const float*)d_in[12];

  char* ws = (char*)d_ws;
  size_t off = 0;
  auto alloc = [&](size_t bytes)->char*{ char* p = ws + off; off += (bytes + 255) & ~(size_t)255; return p; };
  unsigned short* W1T      = (unsigned short*)alloc((size_t)1024*128*2);
  unsigned short* W2T      = (unsigned short*)alloc((size_t)128*128*2);
  unsigned short* Wg1T     = (unsigned short*)alloc((size_t)256*128*2);
  int*            rank     = (int*)alloc((size_t)EE*4);
  float2*         scp      = (float2*)alloc((size_t)EE*8);
  int*            row_ptr  = (int*)alloc((size_t)(NN+1)*4);
  int*            counts   = (int*)alloc((size_t)NN*4);
  int*            lexcl    = (int*)alloc((size_t)NN*4);
  int*            bsum     = (int*)alloc((size_t)256*4);
  unsigned short* h1       = (unsigned short*)alloc((size_t)NN*128*2);
  unsigned short* UH_A     = (unsigned short*)alloc((size_t)NN*256*2);
  unsigned short* UH_B     = (unsigned short*)alloc((size_t)NN*256*2);
  float*          Vf       = (float*)alloc((size_t)NN*128*4);
  unsigned short* Xb       = (unsigned short*)alloc((size_t)NN*CC*2);

  hipMemsetAsync(counts, 0, (size_t)NN*4, stream);
  // fused: hist (first) + weight prep + X->bf16 streaming conversion
  k_conv_hist_prep<<<EDGE_BLKS + PREP_BLKS + CONV_BLKS, 256, 0, stream>>>(
      X, Xb, src, dst, counts, rank, W1, W2, Wg1, W1T, W2T, Wg1T);

  k_scan1<<<SCAN_BLKS, 256, 0, stream>>>(counts, lexcl, bsum);
  k_scan3<<<SCAN_BLKS, 256, 0, stream>>>(lexcl, bsum, row_ptr);

  // fused: encoder GEMM1 (bf16 A) + CSR fill
  k_enc1_fill<<<ENC_BLKS + EDGE_BLKS, 256, 0, stream>>>(
      Xb, W1T, b1, h1, src, dst, base_w, rho, row_ptr, rank, scp);

  k_uvA<<<UV_BLKS, 256, 0, stream>>>(h1, W2T, b2, Wg1T, bg1, UH_A, Vf);

  // layer 1: writes h bf16 directly into UH_B h-half
  k_gate_agg<<<12500, 256, 0, stream>>>(UH_A, Vf, row_ptr, scp, Wg2, bg2, nullptr, UH_B);
  // layer-1 node tables from UH_B h-half
  k_uvB<<<UV_BLKS, 256, 0, stream>>>(Wg1T, bg1, UH_B, Vf);
  // layer 2: final output f32
  k_gate_agg<<<12500, 256, 0, stream>>>(UH_B, Vf, row_ptr, scp, Wg2, bg2, (float*)d_out, nullptr);
}

// Round 18
// 493.008 us; speedup vs baseline: 1.0017x; 1.0017x over previous
//
#include <hip/hip_runtime.h>
#include <stdint.h>

#define NN 50000
#define CC 1024
#define HH 128
#define EE 1600000
#define EPSV 1e-8f
#define SCAN_BLKS 196        // ceil(NN/256)
#define ENC_BLKS 782         // encoder tile blocks (64 rows)
#define UV_BLKS 782
#define EDGE_BLKS (EE/256)   // 6250
#define CONV_BLKS 25000      // X->bf16: 51.2M elems / (256*8)
#define PREP_BLKS 704        // weight prep span
#define CPAD 32              // counters padded to 128B lines

typedef __attribute__((ext_vector_type(8))) short bf16x8;
typedef __attribute__((ext_vector_type(4))) float f32x4;
typedef __attribute__((ext_vector_type(2))) float f32x2;

__device__ __forceinline__ unsigned short f32_to_bf16(float f){
  union { float f; uint32_t u; } cv; cv.f = f;
  uint32_t u = cv.u;
  return (unsigned short)((u + 0x7FFFu + ((u >> 16) & 1u)) >> 16);
}
__device__ __forceinline__ float bf16lo_to_f32(uint32_t w){
  union { uint32_t u; float f; } cv; cv.u = w << 16; return cv.f;
}
__device__ __forceinline__ float bf16hi_to_f32(uint32_t w){
  union { uint32_t u; float f; } cv; cv.u = w & 0xFFFF0000u; return cv.f;
}

// DPP cross-lane add within a 16-lane row (xor1, xor2, ^7-in-8, mirror-16)
#define DPP_ADD(x, ctrl) ((x) + __int_as_float(__builtin_amdgcn_update_dpp(0, __float_as_int(x), (ctrl), 0xF, 0xF, true)))

// async global->LDS 16B DMA
#define GLOAD_LDS16(g, l) __builtin_amdgcn_global_load_lds( \
    (const __attribute__((address_space(1))) uint32_t*)(g), \
    (__attribute__((address_space(3))) uint32_t*)(l), 16, 0, 0)

// ---------------- FUSED: hist (line-padded counters) + prep + X->bf16 ----------------

__global__ __launch_bounds__(256) void k_conv_hist_prep(
    const float* __restrict__ X, unsigned short* __restrict__ Xb,
    const int* __restrict__ src, const int* __restrict__ dst,
    int* __restrict__ counts, int* __restrict__ rank,
    const float* __restrict__ W1, const float* __restrict__ W2,
    const float* __restrict__ Wg1,
    unsigned short* __restrict__ W1T, unsigned short* __restrict__ W2T,
    unsigned short* __restrict__ Wg1T)
{
  const int b = blockIdx.x;
  if(b < EDGE_BLKS){                       // hist + rank, one counter per 128B line
    int e = b*256 + threadIdx.x;
    if(e < EE) rank[e] = atomicAdd(&counts[(size_t)dst[e]*CPAD], 1);
    return;
  }
  if(b < EDGE_BLKS + PREP_BLKS){           // weight prep
    int idx = (b - EDGE_BLKS)*256 + threadIdx.x;
    if(idx < 131072){                                 // W1T[n][k] = W1[k][n]
      int n = idx >> 10, k = idx & 1023;
      W1T[idx] = f32_to_bf16(W1[k*128 + n]);
    } else if(idx < 131072 + 16384){                  // W2T[n][k] = W2[k][n]
      int i = idx - 131072;
      int n = i >> 7, k = i & 127;
      W2T[i] = f32_to_bf16(W2[k*128 + n]);
    } else if(idx < 131072 + 16384 + 32768){          // Wg1T[c][k]
      int i = idx - 131072 - 16384;
      int c = i >> 7, k = i & 127;
      int row = (c < 128) ? k : (128 + k);
      int col = (c < 128) ? c : (c - 128);
      Wg1T[i] = f32_to_bf16(Wg1[row*128 + col]);
    }
    return;
  }
  // streaming X -> bf16
  const size_t i = (((size_t)(b - EDGE_BLKS - PREP_BLKS))*256 + threadIdx.x)*8;
  f32x4 v0 = *(const f32x4*)(X + i);
  f32x4 v1 = *(const f32x4*)(X + i + 4);
  union { bf16x8 v; unsigned short s[8]; } pk;
  #pragma unroll
  for(int j = 0; j < 4; j++){ pk.s[j] = f32_to_bf16(v0[j]); pk.s[4+j] = f32_to_bf16(v1[j]); }
  *(bf16x8*)(Xb + i) = pk.v;
}

// ---------------- scans over NN dst counts (2 launches) ----------------

__global__ __launch_bounds__(256) void k_scan1(const int* __restrict__ counts,
    int* __restrict__ lexcl, int* __restrict__ bsum){
  __shared__ int buf[256];
  const int t = threadIdx.x, i = blockIdx.x*256 + t;
  int v = (i < NN) ? counts[(size_t)i*CPAD] : 0;
  buf[t] = v;
  __syncthreads();
  for(int off = 1; off < 256; off <<= 1){
    int add = (t >= off) ? buf[t-off] : 0;
    __syncthreads();
    buf[t] += add;
    __syncthreads();
  }
  if(i < NN) lexcl[i] = buf[t] - v;
  if(t == 255) bsum[blockIdx.x] = buf[255];
}

// merged: each block reduces its bsum prefix locally, then adds to lexcl
__global__ __launch_bounds__(256) void k_scan3(const int* __restrict__ lexcl,
    const int* __restrict__ bsum, int* __restrict__ row_ptr){
  __shared__ int red[256];
  const int t = threadIdx.x, b = blockIdx.x;
  red[t] = (t < b) ? bsum[t] : 0;     // b < 196 <= 256
  __syncthreads();
  for(int off = 1; off < 256; off <<= 1){
    int add = (t >= off) ? red[t-off] : 0;
    __syncthreads();
    red[t] += add;
    __syncthreads();
  }
  const int bexcl = red[255];
  const int i = b*256 + t;
  if(i < NN) row_ptr[i] = lexcl[i] + bexcl;
  if(i == 0) row_ptr[NN] = EE;
}

// ---------------- FUSED: encoder GEMM1 (bf16 A) + CSR fill ----------------

__global__ __launch_bounds__(256) void k_enc1_fill(
    const unsigned short* __restrict__ Xb, const unsigned short* __restrict__ W1T,
    const float* __restrict__ b1, unsigned short* __restrict__ h1,
    const int* __restrict__ src, const int* __restrict__ dst,
    const float* __restrict__ base_w, const float* __restrict__ rho_raw,
    const int* __restrict__ row_ptr, const int* __restrict__ rank,
    float2* __restrict__ scp)
{
  __shared__ __attribute__((aligned(16))) unsigned short Ab[2][64*32];    // 4KB each
  __shared__ __attribute__((aligned(16))) unsigned short Bf[2][128*32];   // 8KB each

  if(blockIdx.x >= ENC_BLKS){
    int e = (blockIdx.x - ENC_BLKS)*256 + threadIdx.x;
    if(e < EE){
      int s = src[e], d = dst[e];
      int p = row_ptr[d] + rank[e];
      float rs = 1.f/(1.f + __expf(-rho_raw[s]));
      float rd = 1.f/(1.f + __expf(-rho_raw[d]));
      scp[p] = make_float2(base_w[e]*rs*rd, __int_as_float(s));
    }
    return;
  }

  const int t = threadIdx.x, w = t >> 6, lane = t & 63;
  const int rowL = lane & 15, kq = lane >> 4;
  const int wm = w >> 1, wn = w & 1;
  const int row0 = blockIdx.x * 64;

  const int a_rl  = w*16 + (lane >> 2);
  const int a_cl  = lane & 3;
  const int akeyW = (a_rl ^ (a_rl >> 2)) & 3;
  int agr = row0 + a_rl; if(agr >= NN) agr = NN-1;
  const unsigned short* a_src = Xb + (size_t)agr*1024 + (a_cl ^ akeyW)*8;
  const int b_rl0 = w*32 + (lane >> 2);
  const int b_cl  = lane & 3;
  const int bkey0 = (b_rl0 ^ (b_rl0 >> 2)) & 3;
  const int bkey1 = ((b_rl0+16) ^ ((b_rl0+16) >> 2)) & 3;
  const unsigned short* b_src0 = W1T + (size_t)b_rl0*1024 + (b_cl ^ bkey0)*8;
  const unsigned short* b_src1 = W1T + (size_t)(b_rl0+16)*1024 + (b_cl ^ bkey1)*8;

  #define STAGE(buf, k0)  do{                                              \
    GLOAD_LDS16(a_src  + (k0), &Ab[buf][(w*16)*32]);                       \
    GLOAD_LDS16(b_src0 + (k0), &Bf[buf][(w*32     )*32]);                  \
    GLOAD_LDS16(b_src1 + (k0), &Bf[buf][(w*32 + 16)*32]);                  \
  }while(0)

  f32x4 acc[2][4] = {};
  const int arow0 = wm*32 + rowL;
  const int keyR  = (rowL ^ (rowL >> 2)) & 3;

  auto COMPUTE = [&](const unsigned short* afb, const unsigned short* bfb){
    bf16x8 af[2];
    #pragma unroll
    for(int mf = 0; mf < 2; mf++)
      af[mf] = *(const bf16x8*)&afb[(arow0 + mf*16)*32 + ((kq ^ keyR) << 3)];
    bf16x8 bfr[4];
    #pragma unroll
    for(int nf = 0; nf < 4; nf++){
      const int br = wn*64 + nf*16 + rowL;
      bfr[nf] = *(const bf16x8*)&bfb[br*32 + ((kq ^ keyR) << 3)];
    }
    #pragma unroll
    for(int mf = 0; mf < 2; mf++)
      #pragma unroll
      for(int nf = 0; nf < 4; nf++)
        acc[mf][nf] = __builtin_amdgcn_mfma_f32_16x16x32_bf16(af[mf], bfr[nf], acc[mf][nf], 0, 0, 0);
  };

  #define STEP(cbuf, sbuf, sk)  do{                                        \
    STAGE(sbuf, (sk)*32);                                                  \
    asm volatile("s_waitcnt vmcnt(3)" ::: "memory");                       \
    __builtin_amdgcn_s_barrier();                                          \
    __builtin_amdgcn_sched_barrier(0);                                     \
    COMPUTE(&Ab[cbuf][0], &Bf[cbuf][0]);                                   \
    __builtin_amdgcn_s_barrier();                                          \
  }while(0)

  STAGE(0, 0);
  for(int tt = 0; tt < 30; tt += 2){
    STEP(0, 1, tt + 1);
    STEP(1, 0, tt + 2);
  }
  STEP(0, 1, 31);
  asm volatile("s_waitcnt vmcnt(0)" ::: "memory");
  __builtin_amdgcn_s_barrier();
  __builtin_amdgcn_sched_barrier(0);
  COMPUTE(&Ab[1][0], &Bf[1][0]);
  #undef STEP
  #undef STAGE

  #pragma unroll
  for(int mf = 0; mf < 2; mf++){
    #pragma unroll
    for(int nf = 0; nf < 4; nf++){
      const int col = wn*64 + nf*16 + rowL;
      const float bv = b1[col];
      #pragma unroll
      for(int r = 0; r < 4; r++){
        const int gr = row0 + wm*32 + mf*16 + kq*4 + r;
        if(gr < NN) h1[(size_t)gr*128 + col] = f32_to_bf16(fmaxf(acc[mf][nf][r] + bv, 0.f));
      }
    }
  }
}

// ---------------- UV phase 2, B-in-registers: wave w owns output cols [64w,64w+64) ----------------

__device__ __forceinline__ void uv_phase2(
    const unsigned short* hs, int row0, int w, int lane,
    const unsigned short* __restrict__ Wg1T, const float* __restrict__ bg1,
    unsigned short* __restrict__ UH, float* __restrict__ Vf)
{
  const int rowL = lane & 15, kq = lane >> 4;
  bf16x8 breg[4][4];
  #pragma unroll
  for(int nt = 0; nt < 4; nt++)
    #pragma unroll
    for(int ks = 0; ks < 4; ks++)
      breg[nt][ks] = *(const bf16x8*)(Wg1T + (size_t)(w*64 + nt*16 + rowL)*128 + ks*32 + kq*8);

  #pragma unroll
  for(int mt = 0; mt < 4; mt++){
    const int r = mt*16 + rowL;
    f32x4 acc[4] = {};
    #pragma unroll
    for(int ks = 0; ks < 4; ks++){
      const int kc = ks*4 + kq;
      bf16x8 a = *(const bf16x8*)&hs[r*128 + ((kc ^ rowL) << 3)];
      #pragma unroll
      for(int nt = 0; nt < 4; nt++)
        acc[nt] = __builtin_amdgcn_mfma_f32_16x16x32_bf16(a, breg[nt][ks], acc[nt], 0, 0, 0);
    }
    #pragma unroll
    for(int nt = 0; nt < 4; nt++){
      const int col = w*64 + nt*16 + rowL;
      #pragma unroll
      for(int rr = 0; rr < 4; rr++){
        const int gr = row0 + mt*16 + kq*4 + rr;
        if(gr < NN){
          if(col < 128) UH[(size_t)gr*256 + col] = f32_to_bf16(acc[nt][rr]);
          else          Vf[(size_t)gr*128 + col - 128] = acc[nt][rr] + bg1[col - 128];
        }
      }
    }
  }
}

// ---------------- k_uvA: h = relu(h1@W2T + b2); writes UH_A=[u|h], Vf ----------------

__global__ __launch_bounds__(256) void k_uvA(
    const unsigned short* __restrict__ h1, const unsigned short* __restrict__ W2T,
    const float* __restrict__ b2, const unsigned short* __restrict__ Wg1T,
    const float* __restrict__ bg1, unsigned short* __restrict__ UH,
    float* __restrict__ Vf)
{
  __shared__ __attribute__((aligned(16))) unsigned short hs[64*128];   // 16 KB
  const int t = threadIdx.x, wave = t >> 6, lane = t & 63;
  const int rowL = lane & 15, kq = lane >> 4;
  const int row0 = blockIdx.x*64;

  int ar = row0 + wave*16 + rowL; if(ar >= NN) ar = NN-1;
  f32x4 acc[8] = {};
  #pragma unroll
  for(int ks = 0; ks < 4; ks++){
    bf16x8 a = *(const bf16x8*)(h1 + (size_t)ar*128 + ks*32 + kq*8);
    #pragma unroll
    for(int nt = 0; nt < 8; nt++){
      bf16x8 b = *(const bf16x8*)(W2T + (nt*16 + rowL)*128 + ks*32 + kq*8);
      acc[nt] = __builtin_amdgcn_mfma_f32_16x16x32_bf16(a, b, acc[nt], 0, 0, 0);
    }
  }
  #pragma unroll
  for(int nt = 0; nt < 8; nt++){
    const int col = nt*16 + rowL;
    const float bv = b2[col];
    #pragma unroll
    for(int r = 0; r < 4; r++){
      const int rw = wave*16 + kq*4 + r;
      const unsigned short hv = f32_to_bf16(fmaxf(acc[nt][r] + bv, 0.f));
      hs[rw*128 + (((col >> 3) ^ (rw & 15)) << 3) + (col & 7)] = hv;
    }
  }
  __syncthreads();
  {
    const int r = t >> 2, gr = row0 + r;
    if(gr < NN){
      #pragma unroll
      for(int j8 = 0; j8 < 4; j8++){
        const int chunk = (t & 3)*4 + j8;
        bf16x8 v = *(const bf16x8*)&hs[r*128 + ((chunk ^ (r & 15)) << 3)];
        *(bf16x8*)&UH[(size_t)gr*256 + 128 + chunk*8] = v;
      }
    }
  }
  uv_phase2(hs, row0, wave, lane, Wg1T, bg1, UH, Vf);
}

// ---------------- k_uvB: reads UH_B h-half (bf16); computes u,v in place ----------------

__global__ __launch_bounds__(256) void k_uvB(
    const unsigned short* __restrict__ Wg1T, const float* __restrict__ bg1,
    unsigned short* __restrict__ UH, float* __restrict__ Vf)
{
  __shared__ __attribute__((aligned(16))) unsigned short hs[64*128];   // 16 KB
  const int t = threadIdx.x, wave = t >> 6, lane = t & 63;
  const int row0 = blockIdx.x*64;

  {
    const int r = t >> 2, gr0 = row0 + r;
    const int gr = (gr0 < NN) ? gr0 : NN-1;
    const unsigned short* p = UH + (size_t)gr*256 + 128 + (t & 3)*32;
    #pragma unroll
    for(int j8 = 0; j8 < 4; j8++){
      bf16x8 v = *(const bf16x8*)(p + j8*8);
      const int chunk = (t & 3)*4 + j8;
      *(bf16x8*)&hs[r*128 + ((chunk ^ (r & 15)) << 3)] = v;
    }
  }
  __syncthreads();
  uv_phase2(hs, row0, wave, lane, Wg1T, bg1, UH, Vf);
}

// ---------------- fused gate + aggregation, CSR, one wave per dst ----------------

__global__ __launch_bounds__(256) void k_gate_agg(
    const unsigned short* __restrict__ UH, const float* __restrict__ Vf,
    const int* __restrict__ row_ptr, const float2* __restrict__ scp,
    const float* __restrict__ Wg2, const float* __restrict__ bg2p,
    float* __restrict__ out_f32, unsigned short* __restrict__ uh_out)
{
  __shared__ float2 ws_s[4][64];
  const int wv = threadIdx.x >> 6, lane = threadIdx.x & 63;
  const int gw = blockIdx.x*4 + wv;
  if(gw >= NN) return;
  const int eq = lane >> 4, li = lane & 15;

  f32x4 va = *(const f32x4*)(Vf + (size_t)gw*128 + li*8);
  f32x4 vb = *(const f32x4*)(Vf + (size_t)gw*128 + li*8 + 4);
  f32x4 wa = *(const f32x4*)(Wg2 + li*8);
  f32x4 wb = *(const f32x4*)(Wg2 + li*8 + 4);
  const float vch[8]  = {va[0],va[1],va[2],va[3],vb[0],vb[1],vb[2],vb[3]};
  const float w2ch[8] = {wa[0],wa[1],wa[2],wa[3],wb[0],wb[1],wb[2],wb[3]};
  const float bg2v = bg2p[0];

  const int beg = row_ptr[gw], end = row_ptr[gw+1];
  float a0 = 0.f, a1 = 0.f, wsum = 0.f;

  for(int base = beg; base < end; base += 64){
    const int nb = min(64, end - base);

    float2 sc_c0, sc_c1; bf16x8 u_c0, u_c1;
    {
      const int i0 = (eq     < nb) ? eq     : 0;
      const int i1 = (4 + eq < nb) ? 4 + eq : 0;
      sc_c0 = scp[base + i0]; sc_c1 = scp[base + i1];
      u_c0 = *(const bf16x8*)&UH[(uint32_t)__float_as_int(sc_c0.y)*256u + li*8];
      u_c1 = *(const bf16x8*)&UH[(uint32_t)__float_as_int(sc_c1.y)*256u + li*8];
    }
    for(int q = 0; q < nb; q += 8){
      float2 sc_n0 = sc_c0, sc_n1 = sc_c1; bf16x8 u_n0 = u_c0, u_n1 = u_c1;
      if(q + 8 < nb){
        const int i0 = (q + 8  + eq < nb) ? q + 8  + eq : 0;
        const int i1 = (q + 12 + eq < nb) ? q + 12 + eq : 0;
        sc_n0 = scp[base + i0]; sc_n1 = scp[base + i1];
        u_n0 = *(const bf16x8*)&UH[(uint32_t)__float_as_int(sc_n0.y)*256u + li*8];
        u_n1 = *(const bf16x8*)&UH[(uint32_t)__float_as_int(sc_n1.y)*256u + li*8];
      }
      { // edge A: idx = q + eq
        union { bf16x8 v; uint32_t u32[4]; } uu; uu.v = u_c0;
        float tacc = 0.f;
        #pragma unroll
        for(int p = 0; p < 4; p++){
          const uint32_t w2b = uu.u32[p];
          tacc += fmaxf(bf16lo_to_f32(w2b) + vch[2*p],   0.f) * w2ch[2*p];
          tacc += fmaxf(bf16hi_to_f32(w2b) + vch[2*p+1], 0.f) * w2ch[2*p+1];
        }
        tacc = DPP_ADD(tacc, 0xB1);
        tacc = DPP_ADD(tacc, 0x4E);
        tacc = DPP_ADD(tacc, 0x141);
        tacc = DPP_ADD(tacc, 0x140);
        const float g = 1.f/(1.f + __expf(-(tacc + bg2v)));
        const int idx = q + eq;
        if(li == 0 && idx < nb) ws_s[wv][idx] = make_float2(sc_c0.x*g, sc_c0.y);
      }
      { // edge B: idx = q + 4 + eq
        union { bf16x8 v; uint32_t u32[4]; } uu; uu.v = u_c1;
        float tacc = 0.f;
        #pragma unroll
        for(int p = 0; p < 4; p++){
          const uint32_t w2b = uu.u32[p];
          tacc += fmaxf(bf16lo_to_f32(w2b) + vch[2*p],   0.f) * w2ch[2*p];
          tacc += fmaxf(bf16hi_to_f32(w2b) + vch[2*p+1], 0.f) * w2ch[2*p+1];
        }
        tacc = DPP_ADD(tacc, 0xB1);
        tacc = DPP_ADD(tacc, 0x4E);
        tacc = DPP_ADD(tacc, 0x141);
        tacc = DPP_ADD(tacc, 0x140);
        const float g = 1.f/(1.f + __expf(-(tacc + bg2v)));
        const int idx = q + 4 + eq;
        if(li == 0 && idx < nb) ws_s[wv][idx] = make_float2(sc_c1.x*g, sc_c1.y);
      }
      sc_c0 = sc_n0; sc_c1 = sc_n1; u_c0 = u_n0; u_c1 = u_n1;
    }

    #pragma unroll 8
    for(int j = 0; j < nb; j++){
      const float2 p = ws_s[wv][j];
      const float w  = p.x;
      const uint32_t s = (uint32_t)__float_as_int(p.y);
      const uint32_t hw = *(const uint32_t*)&UH[s*256u + 128u + lane*2];
      a0 += w*bf16lo_to_f32(hw);
      a1 += w*bf16hi_to_f32(hw);
      wsum += w;
    }
  }
  const float inv = 1.f/(wsum + EPSV);
  const float r0 = a0*inv, r1 = a1*inv;
  if(uh_out){
    const uint32_t packed = (uint32_t)f32_to_bf16(r0) | ((uint32_t)f32_to_bf16(r1) << 16);
    *(uint32_t*)&uh_out[(size_t)gw*256 + 128 + lane*2] = packed;
  } else {
    const size_t o = (size_t)gw*128 + lane*2;
    *(f32x2*)&out_f32[o] = (f32x2){r0, r1};
  }
}

// ---------------- launch ----------------

extern "C" void kernel_launch(void* const* d_in, const int* in_sizes, int n_in,
                              void* d_out, int out_size, void* d_ws, size_t ws_size,
                              hipStream_t stream) {
  (void)in_sizes; (void)n_in; (void)out_size; (void)ws_size;
  const float* X      = (const float*)d_in[0];
  const int*   src    = (const int*)d_in[1];
  const int*   dst    = (const int*)d_in[2];
  const float* base_w = (const float*)d_in[3];
  const float* W1     = (const float*)d_in[4];
  const float* b1     = (const float*)d_in[5];
  const float* W2     = (const float*)d_in[6];
  const float* b2     = (const float*)d_in[7];
  const float* Wg1    = (const float*)d_in[8];
  const float* bg1    = (const float*)d_in[9];
  const float* Wg2    = (const float*)d_in[10];
  const float* bg2    = (const float*)d_in[11];
  const float* rho    = (const float*)d_in[12];

  char* ws = (char*)d_ws;
  size_t off = 0;
  auto alloc = [&](size_t bytes)->char*{ char* p = ws + off; off += (bytes + 255) & ~(size_t)255; return p; };
  unsigned short* W1T      = (unsigned short*)alloc((size_t)1024*128*2);
  unsigned short* W2T      = (unsigned short*)alloc((size_t)128*128*2);
  unsigned short* Wg1T     = (unsigned short*)alloc((size_t)256*128*2);
  int*            rank     = (int*)alloc((size_t)EE*4);
  float2*         scp      = (float2*)alloc((size_t)EE*8);
  int*            row_ptr  = (int*)alloc((size_t)(NN+1)*4);
  int*            counts   = (int*)alloc((size_t)NN*CPAD*4);   // 6.4MB, 1 counter / 128B line
  int*            lexcl    = (int*)alloc((size_t)NN*4);
  int*            bsum     = (int*)alloc((size_t)256*4);
  unsigned short* h1       = (unsigned short*)alloc((size_t)NN*128*2);
  unsigned short* UH_A     = (unsigned short*)alloc((size_t)NN*256*2);
  unsigned short* UH_B     = (unsigned short*)alloc((size_t)NN*256*2);
  float*          Vf       = (float*)alloc((size_t)NN*128*4);
  unsigned short* Xb       = (unsigned short*)alloc((size_t)NN*CC*2);

  hipMemsetAsync(counts, 0, (size_t)NN*CPAD*4, stream);
  // fused: hist (padded counters) + weight prep + X->bf16 streaming conversion
  k_conv_hist_prep<<<EDGE_BLKS + PREP_BLKS + CONV_BLKS, 256, 0, stream>>>(
      X, Xb, src, dst, counts, rank, W1, W2, Wg1, W1T, W2T, Wg1T);

  k_scan1<<<SCAN_BLKS, 256, 0, stream>>>(counts, lexcl, bsum);
  k_scan3<<<SCAN_BLKS, 256, 0, stream>>>(lexcl, bsum, row_ptr);

  // fused: encoder GEMM1 (bf16 A) + CSR fill
  k_enc1_fill<<<ENC_BLKS + EDGE_BLKS, 256, 0, stream>>>(
      Xb, W1T, b1, h1, src, dst, base_w, rho, row_ptr, rank, scp);

  k_uvA<<<UV_BLKS, 256, 0, stream>>>(h1, W2T, b2, Wg1T, bg1, UH_A, Vf);

  // layer 1: writes h bf16 directly into UH_B h-half
  k_gate_agg<<<12500, 256, 0, stream>>>(UH_A, Vf, row_ptr, scp, Wg2, bg2, nullptr, UH_B);
  // layer-1 node tables from UH_B h-half
  k_uvB<<<UV_BLKS, 256, 0, stream>>>(Wg1T, bg1, UH_B, Vf);
  // layer 2: final output f32
  k_gate_agg<<<12500, 256, 0, stream>>>(UH_B, Vf, row_ptr, scp, Wg2, bg2, (float*)d_out, nullptr);
}

// Round 19
// 444.608 us; speedup vs baseline: 1.1107x; 1.1089x over previous
//
#include <hip/hip_runtime.h>
#include <stdint.h>

#define NN 50000
#define CC 1024
#define HH 128
#define EE 1600000
#define EPSV 1e-8f
#define SCAN_BLKS 196        // ceil(NN/256)
#define ENC_BLKS 782         // encoder tile blocks (64 rows)
#define UV_BLKS 782
#define EDGE_BLKS (EE/256)   // 6250
#define PREP_BLKS 704        // weight prep span

typedef __attribute__((ext_vector_type(8))) short bf16x8;
typedef __attribute__((ext_vector_type(4))) float f32x4;
typedef __attribute__((ext_vector_type(2))) float f32x2;

__device__ __forceinline__ unsigned short f32_to_bf16(float f){
  union { float f; uint32_t u; } cv; cv.f = f;
  uint32_t u = cv.u;
  return (unsigned short)((u + 0x7FFFu + ((u >> 16) & 1u)) >> 16);
}
__device__ __forceinline__ float bf16lo_to_f32(uint32_t w){
  union { uint32_t u; float f; } cv; cv.u = w << 16; return cv.f;
}
__device__ __forceinline__ float bf16hi_to_f32(uint32_t w){
  union { uint32_t u; float f; } cv; cv.u = w & 0xFFFF0000u; return cv.f;
}

// DPP cross-lane add within a 16-lane row (xor1, xor2, ^7-in-8, mirror-16)
#define DPP_ADD(x, ctrl) ((x) + __int_as_float(__builtin_amdgcn_update_dpp(0, __float_as_int(x), (ctrl), 0xF, 0xF, true)))

// async global->LDS 16B DMA
#define GLOAD_LDS16(g, l) __builtin_amdgcn_global_load_lds( \
    (const __attribute__((address_space(1))) uint32_t*)(g), \
    (__attribute__((address_space(3))) uint32_t*)(l), 16, 0, 0)

// ---------------- weight prep: W1T, W2T, Wg1T ----------------

__global__ __launch_bounds__(256) void k_prep_all(
    const float* __restrict__ W1, const float* __restrict__ W2,
    const float* __restrict__ Wg1,
    unsigned short* __restrict__ W1T, unsigned short* __restrict__ W2T,
    unsigned short* __restrict__ Wg1T){
  int idx = blockIdx.x*256 + threadIdx.x;
  if(idx < 131072){                                   // W1T[n][k] = W1[k][n]
    int n = idx >> 10, k = idx & 1023;
    W1T[idx] = f32_to_bf16(W1[k*128 + n]);
  } else if(idx < 131072 + 16384){                    // W2T[n][k] = W2[k][n]
    int i = idx - 131072;
    int n = i >> 7, k = i & 127;
    W2T[i] = f32_to_bf16(W2[k*128 + n]);
  } else if(idx < 131072 + 16384 + 32768){            // Wg1T[c][k]
    int i = idx - 131072 - 16384;
    int c = i >> 7, k = i & 127;
    int row = (c < 128) ? k : (128 + k);
    int col = (c < 128) ? c : (c - 128);
    Wg1T[i] = f32_to_bf16(Wg1[row*128 + col]);
  }
}

// ---------------- FUSED: encoder GEMM1 (f32 X, read once at its floor) + hist ----------------
// enc1: 64-row M-tile, 2-buffer global_load_lds pipeline, counted vmcnt(4).
// A staged f32 (converted at fragment read), swizzled global source (T21).
// hist (blocks >= ENC_BLKS): rank[e] = atomicAdd(counts[dst], 1).

__global__ __launch_bounds__(256) void k_enc1_hist(
    const float* __restrict__ X, const unsigned short* __restrict__ W1T,
    const float* __restrict__ b1, unsigned short* __restrict__ h1,
    const int* __restrict__ dst, int* __restrict__ counts, int* __restrict__ rank)
{
  __shared__ __attribute__((aligned(16))) float          Af[2][64*32];    // 8KB each
  __shared__ __attribute__((aligned(16))) unsigned short Bf[2][128*32];   // 8KB each

  if(blockIdx.x >= ENC_BLKS){
    int e = (blockIdx.x - ENC_BLKS)*256 + threadIdx.x;
    if(e < EE) rank[e] = atomicAdd(&counts[dst[e]], 1);
    return;
  }

  const int t = threadIdx.x, w = t >> 6, lane = t & 63;
  const int rowL = lane & 15, kq = lane >> 4;
  const int wm = w >> 1, wn = w & 1;
  const int row0 = blockIdx.x * 64;

  const int a_rl0 = w*16 + (lane >> 3);
  const int a_cl  = lane & 7;
  int agr0 = row0 + a_rl0;     if(agr0 >= NN) agr0 = NN-1;
  int agr1 = row0 + a_rl0 + 8; if(agr1 >= NN) agr1 = NN-1;
  const float* a_src0 = X + (size_t)agr0*1024 + (a_cl ^ (a_rl0 & 7))*4;
  const float* a_src1 = X + (size_t)agr1*1024 + (a_cl ^ ((a_rl0+8) & 7))*4;
  const int b_rl0 = w*32 + (lane >> 2);
  const int b_cl  = lane & 3;
  const int bkey0 = (b_rl0 ^ (b_rl0 >> 2)) & 3;
  const int bkey1 = ((b_rl0+16) ^ ((b_rl0+16) >> 2)) & 3;
  const unsigned short* b_src0 = W1T + (size_t)b_rl0*1024 + (b_cl ^ bkey0)*8;
  const unsigned short* b_src1 = W1T + (size_t)(b_rl0+16)*1024 + (b_cl ^ bkey1)*8;

  #define STAGE(buf, k0)  do{                                              \
    GLOAD_LDS16(a_src0 + (k0), &Af[buf][(w*16    )*32]);                   \
    GLOAD_LDS16(a_src1 + (k0), &Af[buf][(w*16 + 8)*32]);                   \
    GLOAD_LDS16(b_src0 + (k0), &Bf[buf][(w*32     )*32]);                  \
    GLOAD_LDS16(b_src1 + (k0), &Bf[buf][(w*32 + 16)*32]);                  \
  }while(0)

  f32x4 acc[2][4] = {};
  const int arow0 = wm*32 + rowL;
  const int akey  = rowL & 7;
  const int bkeyR = (rowL ^ (rowL >> 2)) & 3;

  auto COMPUTE = [&](const float* afb, const unsigned short* bfb){
    bf16x8 af[2];
    #pragma unroll
    for(int mf = 0; mf < 2; mf++){
      const int ar = arow0 + mf*16;
      f32x4 x0 = *(const f32x4*)&afb[ar*32 + (((2*kq  ) ^ akey) << 2)];
      f32x4 x1 = *(const f32x4*)&afb[ar*32 + (((2*kq+1) ^ akey) << 2)];
      union { bf16x8 v; unsigned short s[8]; } pk;
      #pragma unroll
      for(int j = 0; j < 4; j++){ pk.s[j] = f32_to_bf16(x0[j]); pk.s[4+j] = f32_to_bf16(x1[j]); }
      af[mf] = pk.v;
    }
    bf16x8 bfr[4];
    #pragma unroll
    for(int nf = 0; nf < 4; nf++){
      const int br = wn*64 + nf*16 + rowL;
      bfr[nf] = *(const bf16x8*)&bfb[br*32 + ((kq ^ bkeyR) << 3)];
    }
    #pragma unroll
    for(int mf = 0; mf < 2; mf++)
      #pragma unroll
      for(int nf = 0; nf < 4; nf++)
        acc[mf][nf] = __builtin_amdgcn_mfma_f32_16x16x32_bf16(af[mf], bfr[nf], acc[mf][nf], 0, 0, 0);
  };

  #define STEP(cbuf, sbuf, sk)  do{                                        \
    STAGE(sbuf, (sk)*32);                                                  \
    asm volatile("s_waitcnt vmcnt(4)" ::: "memory");                       \
    __builtin_amdgcn_s_barrier();                                          \
    __builtin_amdgcn_sched_barrier(0);                                     \
    COMPUTE(&Af[cbuf][0], &Bf[cbuf][0]);                                   \
    __builtin_amdgcn_s_barrier();                                          \
  }while(0)

  STAGE(0, 0);
  for(int tt = 0; tt < 30; tt += 2){
    STEP(0, 1, tt + 1);
    STEP(1, 0, tt + 2);
  }
  STEP(0, 1, 31);
  asm volatile("s_waitcnt vmcnt(0)" ::: "memory");
  __builtin_amdgcn_s_barrier();
  __builtin_amdgcn_sched_barrier(0);
  COMPUTE(&Af[1][0], &Bf[1][0]);
  #undef STEP
  #undef STAGE

  // epilogue: bias + relu + bf16 store. C frag: row = kq*4+r, col = rowL.
  #pragma unroll
  for(int mf = 0; mf < 2; mf++){
    #pragma unroll
    for(int nf = 0; nf < 4; nf++){
      const int col = wn*64 + nf*16 + rowL;
      const float bv = b1[col];
      #pragma unroll
      for(int r = 0; r < 4; r++){
        const int gr = row0 + wm*32 + mf*16 + kq*4 + r;
        if(gr < NN) h1[(size_t)gr*128 + col] = f32_to_bf16(fmaxf(acc[mf][nf][r] + bv, 0.f));
      }
    }
  }
}

// ---------------- scans over NN dst counts (2 launches) ----------------

__global__ __launch_bounds__(256) void k_scan1(const int* __restrict__ counts,
    int* __restrict__ lexcl, int* __restrict__ bsum){
  __shared__ int buf[256];
  const int t = threadIdx.x, i = blockIdx.x*256 + t;
  int v = (i < NN) ? counts[i] : 0;
  buf[t] = v;
  __syncthreads();
  for(int off = 1; off < 256; off <<= 1){
    int add = (t >= off) ? buf[t-off] : 0;
    __syncthreads();
    buf[t] += add;
    __syncthreads();
  }
  if(i < NN) lexcl[i] = buf[t] - v;
  if(t == 255) bsum[blockIdx.x] = buf[255];
}

// merged: each block reduces its bsum prefix locally, then adds to lexcl
__global__ __launch_bounds__(256) void k_scan3(const int* __restrict__ lexcl,
    const int* __restrict__ bsum, int* __restrict__ row_ptr){
  __shared__ int red[256];
  const int t = threadIdx.x, b = blockIdx.x;
  red[t] = (t < b) ? bsum[t] : 0;     // b < 196 <= 256
  __syncthreads();
  for(int off = 1; off < 256; off <<= 1){
    int add = (t >= off) ? red[t-off] : 0;
    __syncthreads();
    red[t] += add;
    __syncthreads();
  }
  const int bexcl = red[255];
  const int i = b*256 + t;
  if(i < NN) row_ptr[i] = lexcl[i] + bexcl;
  if(i == 0) row_ptr[NN] = EE;
}

// ---------------- UV phase 2, B-in-registers: wave w owns output cols [64w,64w+64) ----------------
// hs: 64 rows x 128 bf16 swizzled (chunk c of row r at c^(r&15)). B-frags from
// L2-resident Wg1T held in 64 VGPR; 4 M-subtiles iterated from LDS. No wgl LDS.

__device__ __forceinline__ void uv_phase2(
    const unsigned short* hs, int row0, int w, int lane,
    const unsigned short* __restrict__ Wg1T, const float* __restrict__ bg1,
    unsigned short* __restrict__ UH, float* __restrict__ Vf)
{
  const int rowL = lane & 15, kq = lane >> 4;
  bf16x8 breg[4][4];
  #pragma unroll
  for(int nt = 0; nt < 4; nt++)
    #pragma unroll
    for(int ks = 0; ks < 4; ks++)
      breg[nt][ks] = *(const bf16x8*)(Wg1T + (size_t)(w*64 + nt*16 + rowL)*128 + ks*32 + kq*8);

  #pragma unroll
  for(int mt = 0; mt < 4; mt++){
    const int r = mt*16 + rowL;
    f32x4 acc[4] = {};
    #pragma unroll
    for(int ks = 0; ks < 4; ks++){
      const int kc = ks*4 + kq;
      bf16x8 a = *(const bf16x8*)&hs[r*128 + ((kc ^ rowL) << 3)];
      #pragma unroll
      for(int nt = 0; nt < 4; nt++)
        acc[nt] = __builtin_amdgcn_mfma_f32_16x16x32_bf16(a, breg[nt][ks], acc[nt], 0, 0, 0);
    }
    #pragma unroll
    for(int nt = 0; nt < 4; nt++){
      const int col = w*64 + nt*16 + rowL;
      #pragma unroll
      for(int rr = 0; rr < 4; rr++){
        const int gr = row0 + mt*16 + kq*4 + rr;
        if(gr < NN){
          if(col < 128) UH[(size_t)gr*256 + col] = f32_to_bf16(acc[nt][rr]);
          else          Vf[(size_t)gr*128 + col - 128] = acc[nt][rr] + bg1[col - 128];
        }
      }
    }
  }
}

// ---------------- FUSED: k_uvA (h = relu(h1@W2T+b2) -> UH_A=[u|h], Vf) + CSR fill ----------------

__global__ __launch_bounds__(256) void k_uvA_fill(
    const unsigned short* __restrict__ h1, const unsigned short* __restrict__ W2T,
    const float* __restrict__ b2, const unsigned short* __restrict__ Wg1T,
    const float* __restrict__ bg1, unsigned short* __restrict__ UH,
    float* __restrict__ Vf,
    const int* __restrict__ src, const int* __restrict__ dst,
    const float* __restrict__ base_w, const float* __restrict__ rho_raw,
    const int* __restrict__ row_ptr, const int* __restrict__ rank,
    float2* __restrict__ scp)
{
  __shared__ __attribute__((aligned(16))) unsigned short hs[64*128];   // 16 KB

  if(blockIdx.x >= UV_BLKS){
    int e = (blockIdx.x - UV_BLKS)*256 + threadIdx.x;
    if(e < EE){
      int s = src[e], d = dst[e];
      int p = row_ptr[d] + rank[e];
      float rs = 1.f/(1.f + __expf(-rho_raw[s]));
      float rd = 1.f/(1.f + __expf(-rho_raw[d]));
      scp[p] = make_float2(base_w[e]*rs*rd, __int_as_float(s));
    }
    return;
  }

  const int t = threadIdx.x, wave = t >> 6, lane = t & 63;
  const int rowL = lane & 15, kq = lane >> 4;
  const int row0 = blockIdx.x*64;

  int ar = row0 + wave*16 + rowL; if(ar >= NN) ar = NN-1;
  f32x4 acc[8] = {};
  #pragma unroll
  for(int ks = 0; ks < 4; ks++){
    bf16x8 a = *(const bf16x8*)(h1 + (size_t)ar*128 + ks*32 + kq*8);
    #pragma unroll
    for(int nt = 0; nt < 8; nt++){
      bf16x8 b = *(const bf16x8*)(W2T + (nt*16 + rowL)*128 + ks*32 + kq*8);
      acc[nt] = __builtin_amdgcn_mfma_f32_16x16x32_bf16(a, b, acc[nt], 0, 0, 0);
    }
  }
  #pragma unroll
  for(int nt = 0; nt < 8; nt++){
    const int col = nt*16 + rowL;
    const float bv = b2[col];
    #pragma unroll
    for(int r = 0; r < 4; r++){
      const int rw = wave*16 + kq*4 + r;
      const unsigned short hv = f32_to_bf16(fmaxf(acc[nt][r] + bv, 0.f));
      hs[rw*128 + (((col >> 3) ^ (rw & 15)) << 3) + (col & 7)] = hv;
    }
  }
  __syncthreads();
  // copy h to UH h-half (coalesced 16B)
  {
    const int r = t >> 2, gr = row0 + r;
    if(gr < NN){
      #pragma unroll
      for(int j8 = 0; j8 < 4; j8++){
        const int chunk = (t & 3)*4 + j8;
        bf16x8 v = *(const bf16x8*)&hs[r*128 + ((chunk ^ (r & 15)) << 3)];
        *(bf16x8*)&UH[(size_t)gr*256 + 128 + chunk*8] = v;
      }
    }
  }
  uv_phase2(hs, row0, wave, lane, Wg1T, bg1, UH, Vf);
}

// ---------------- k_uvB: reads UH_B h-half (bf16); computes u,v in place ----------------

__global__ __launch_bounds__(256) void k_uvB(
    const unsigned short* __restrict__ Wg1T, const float* __restrict__ bg1,
    unsigned short* __restrict__ UH, float* __restrict__ Vf)
{
  __shared__ __attribute__((aligned(16))) unsigned short hs[64*128];   // 16 KB
  const int t = threadIdx.x, wave = t >> 6, lane = t & 63;
  const int row0 = blockIdx.x*64;

  {
    const int r = t >> 2, gr0 = row0 + r;
    const int gr = (gr0 < NN) ? gr0 : NN-1;
    const unsigned short* p = UH + (size_t)gr*256 + 128 + (t & 3)*32;
    #pragma unroll
    for(int j8 = 0; j8 < 4; j8++){
      bf16x8 v = *(const bf16x8*)(p + j8*8);
      const int chunk = (t & 3)*4 + j8;
      *(bf16x8*)&hs[r*128 + ((chunk ^ (r & 15)) << 3)] = v;
    }
  }
  __syncthreads();
  uv_phase2(hs, row0, wave, lane, Wg1T, bg1, UH, Vf);
}

// ---------------- fused gate + aggregation, CSR, one wave per dst ----------------

__global__ __launch_bounds__(256) void k_gate_agg(
    const unsigned short* __restrict__ UH, const float* __restrict__ Vf,
    const int* __restrict__ row_ptr, const float2* __restrict__ scp,
    const float* __restrict__ Wg2, const float* __restrict__ bg2p,
    float* __restrict__ out_f32, unsigned short* __restrict__ uh_out)
{
  __shared__ float2 ws_s[4][64];
  const int wv = threadIdx.x >> 6, lane = threadIdx.x & 63;
  const int gw = blockIdx.x*4 + wv;
  if(gw >= NN) return;
  const int eq = lane >> 4, li = lane & 15;

  f32x4 va = *(const f32x4*)(Vf + (size_t)gw*128 + li*8);
  f32x4 vb = *(const f32x4*)(Vf + (size_t)gw*128 + li*8 + 4);
  f32x4 wa = *(const f32x4*)(Wg2 + li*8);
  f32x4 wb = *(const f32x4*)(Wg2 + li*8 + 4);
  const float vch[8]  = {va[0],va[1],va[2],va[3],vb[0],vb[1],vb[2],vb[3]};
  const float w2ch[8] = {wa[0],wa[1],wa[2],wa[3],wb[0],wb[1],wb[2],wb[3]};
  const float bg2v = bg2p[0];

  const int beg = row_ptr[gw], end = row_ptr[gw+1];
  float a0 = 0.f, a1 = 0.f, wsum = 0.f;

  for(int base = beg; base < end; base += 64){
    const int nb = min(64, end - base);

    float2 sc_c0, sc_c1; bf16x8 u_c0, u_c1;
    {
      const int i0 = (eq     < nb) ? eq     : 0;
      const int i1 = (4 + eq < nb) ? 4 + eq : 0;
      sc_c0 = scp[base + i0]; sc_c1 = scp[base + i1];
      u_c0 = *(const bf16x8*)&UH[(uint32_t)__float_as_int(sc_c0.y)*256u + li*8];
      u_c1 = *(const bf16x8*)&UH[(uint32_t)__float_as_int(sc_c1.y)*256u + li*8];
    }
    for(int q = 0; q < nb; q += 8){
      float2 sc_n0 = sc_c0, sc_n1 = sc_c1; bf16x8 u_n0 = u_c0, u_n1 = u_c1;
      if(q + 8 < nb){
        const int i0 = (q + 8  + eq < nb) ? q + 8  + eq : 0;
        const int i1 = (q + 12 + eq < nb) ? q + 12 + eq : 0;
        sc_n0 = scp[base + i0]; sc_n1 = scp[base + i1];
        u_n0 = *(const bf16x8*)&UH[(uint32_t)__float_as_int(sc_n0.y)*256u + li*8];
        u_n1 = *(const bf16x8*)&UH[(uint32_t)__float_as_int(sc_n1.y)*256u + li*8];
      }
      { // edge A: idx = q + eq
        union { bf16x8 v; uint32_t u32[4]; } uu; uu.v = u_c0;
        float tacc = 0.f;
        #pragma unroll
        for(int p = 0; p < 4; p++){
          const uint32_t w2b = uu.u32[p];
          tacc += fmaxf(bf16lo_to_f32(w2b) + vch[2*p],   0.f) * w2ch[2*p];
          tacc += fmaxf(bf16hi_to_f32(w2b) + vch[2*p+1], 0.f) * w2ch[2*p+1];
        }
        tacc = DPP_ADD(tacc, 0xB1);
        tacc = DPP_ADD(tacc, 0x4E);
        tacc = DPP_ADD(tacc, 0x141);
        tacc = DPP_ADD(tacc, 0x140);
        const float g = 1.f/(1.f + __expf(-(tacc + bg2v)));
        const int idx = q + eq;
        if(li == 0 && idx < nb) ws_s[wv][idx] = make_float2(sc_c0.x*g, sc_c0.y);
      }
      { // edge B: idx = q + 4 + eq
        union { bf16x8 v; uint32_t u32[4]; } uu; uu.v = u_c1;
        float tacc = 0.f;
        #pragma unroll
        for(int p = 0; p < 4; p++){
          const uint32_t w2b = uu.u32[p];
          tacc += fmaxf(bf16lo_to_f32(w2b) + vch[2*p],   0.f) * w2ch[2*p];
          tacc += fmaxf(bf16hi_to_f32(w2b) + vch[2*p+1], 0.f) * w2ch[2*p+1];
        }
        tacc = DPP_ADD(tacc, 0xB1);
        tacc = DPP_ADD(tacc, 0x4E);
        tacc = DPP_ADD(tacc, 0x141);
        tacc = DPP_ADD(tacc, 0x140);
        const float g = 1.f/(1.f + __expf(-(tacc + bg2v)));
        const int idx = q + 4 + eq;
        if(li == 0 && idx < nb) ws_s[wv][idx] = make_float2(sc_c1.x*g, sc_c1.y);
      }
      sc_c0 = sc_n0; sc_c1 = sc_n1; u_c0 = u_n0; u_c1 = u_n1;
    }

    #pragma unroll 8
    for(int j = 0; j < nb; j++){
      const float2 p = ws_s[wv][j];
      const float w  = p.x;
      const uint32_t s = (uint32_t)__float_as_int(p.y);
      const uint32_t hw = *(const uint32_t*)&UH[s*256u + 128u + lane*2];
      a0 += w*bf16lo_to_f32(hw);
      a1 += w*bf16hi_to_f32(hw);
      wsum += w;
    }
  }
  const float inv = 1.f/(wsum + EPSV);
  const float r0 = a0*inv, r1 = a1*inv;
  if(uh_out){
    const uint32_t packed = (uint32_t)f32_to_bf16(r0) | ((uint32_t)f32_to_bf16(r1) << 16);
    *(uint32_t*)&uh_out[(size_t)gw*256 + 128 + lane*2] = packed;
  } else {
    const size_t o = (size_t)gw*128 + lane*2;
    *(f32x2*)&out_f32[o] = (f32x2){r0, r1};
  }
}

// ---------------- launch ----------------

extern "C" void kernel_launch(void* const* d_in, const int* in_sizes, int n_in,
                              void* d_out, int out_size, void* d_ws, size_t ws_size,
                              hipStream_t stream) {
  (void)in_sizes; (void)n_in; (void)out_size; (void)ws_size;
  const float* X      = (const float*)d_in[0];
  const int*   src    = (const int*)d_in[1];
  const int*   dst    = (const int*)d_in[2];
  const float* base_w = (const float*)d_in[3];
  const float* W1     = (const float*)d_in[4];
  const float* b1     = (const float*)d_in[5];
  const float* W2     = (const float*)d_in[6];
  const float* b2     = (const float*)d_in[7];
  const float* Wg1    = (const float*)d_in[8];
  const float* bg1    = (const float*)d_in[9];
  const float* Wg2    = (const float*)d_in[10];
  const float* bg2    = (const float*)d_in[11];
  const float* rho    = (const float*)d_in[12];

  char* ws = (char*)d_ws;
  size_t off = 0;
  auto alloc = [&](size_t bytes)->char*{ char* p = ws + off; off += (bytes + 255) & ~(size_t)255; return p; };
  unsigned short* W1T      = (unsigned short*)alloc((size_t)1024*128*2);
  unsigned short* W2T      = (unsigned short*)alloc((size_t)128*128*2);
  unsigned short* Wg1T     = (unsigned short*)alloc((size_t)256*128*2);
  int*            rank     = (int*)alloc((size_t)EE*4);
  float2*         scp      = (float2*)alloc((size_t)EE*8);
  int*            row_ptr  = (int*)alloc((size_t)(NN+1)*4);
  int*            counts   = (int*)alloc((size_t)NN*4);
  int*            lexcl    = (int*)alloc((size_t)NN*4);
  int*            bsum     = (int*)alloc((size_t)256*4);
  unsigned short* h1       = (unsigned short*)alloc((size_t)NN*128*2);
  unsigned short* UH_A     = (unsigned short*)alloc((size_t)NN*256*2);
  unsigned short* UH_B     = (unsigned short*)alloc((size_t)NN*256*2);
  float*          Vf       = (float*)alloc((size_t)NN*128*4);

  hipMemsetAsync(counts, 0, (size_t)NN*4, stream);
  k_prep_all<<<PREP_BLKS, 256, 0, stream>>>(W1, W2, Wg1, W1T, W2T, Wg1T);

  // fused: encoder GEMM1 (X read once, at its service floor) + histogram
  k_enc1_hist<<<ENC_BLKS + EDGE_BLKS, 256, 0, stream>>>(
      X, W1T, b1, h1, dst, counts, rank);

  k_scan1<<<SCAN_BLKS, 256, 0, stream>>>(counts, lexcl, bsum);
  k_scan3<<<SCAN_BLKS, 256, 0, stream>>>(lexcl, bsum, row_ptr);

  // fused: uvA (layer-1 node tables) + CSR fill
  k_uvA_fill<<<UV_BLKS + EDGE_BLKS, 256, 0, stream>>>(
      h1, W2T, b2, Wg1T, bg1, UH_A, Vf, src, dst, base_w, rho, row_ptr, rank, scp);

  // layer 1: writes h bf16 directly into UH_B h-half
  k_gate_agg<<<12500, 256, 0, stream>>>(UH_A, Vf, row_ptr, scp, Wg2, bg2, nullptr, UH_B);
  // layer-1 node tables from UH_B h-half
  k_uvB<<<UV_BLKS, 256, 0, stream>>>(Wg1T, bg1, UH_B, Vf);
  // layer 2: final output f32
  k_gate_agg<<<12500, 256, 0, stream>>>(UH_B, Vf, row_ptr, scp, Wg2, bg2, (float*)d_out, nullptr);
}